// Round 1
// baseline (1395.747 us; speedup 1.0000x reference)
//
#include <hip/hip_runtime.h>
#include <hip/hip_bf16.h>
#include <math.h>

// GCN 3-layer inference. N=100000 nodes, E=3200000 edges, feats 128->4->2->1.
// Degrees/norms identical across layers -> computed once.
// ws layout (floats): [0,N) deg->dinv | [N,5N) h1 | [5N,9N) agg1 |
//                     [9N,11N) h2 | [11N,13N) agg2 | [13N,14N) h3 | [14N,15N) agg3
// Total 15N floats = 6 MB.

#define TPB 256

__global__ void k_init_deg(float* __restrict__ deg, int n) {
    int v = blockIdx.x * blockDim.x + threadIdx.x;
    if (v < n) deg[v] = 1.0f;  // self-loop
}

__global__ void k_count_deg(const int* __restrict__ dst, float* __restrict__ deg, int E) {
    int e = blockIdx.x * blockDim.x + threadIdx.x;
    if (e < E) unsafeAtomicAdd(&deg[dst[e]], 1.0f);
}

// Layer-1 GEMM (128->4) + dinv finalize + self-loop init of agg1.
// Quad-per-node: 4 lanes per node, each lane covers 32 features interleaved
// (lane p reads float4 chunks p, p+4, ..., p+28) -> a wave's loads cover
// 16 aligned 64B lines per step (fully coalesced). Reduce via __shfl_xor.
__global__ __launch_bounds__(TPB) void k_node1(
    const float* __restrict__ x, const float* __restrict__ W1,
    float* __restrict__ dinv /* holds deg on entry */,
    float* __restrict__ h1, float* __restrict__ agg1, int n) {
    __shared__ float Ws[512];  // W1 is [128][4] row-major
    for (int i = threadIdx.x; i < 512; i += TPB) Ws[i] = W1[i];
    __syncthreads();
    int t = blockIdx.x * TPB + threadIdx.x;
    int v = t >> 2, p = t & 3;
    if (v >= n) return;
    const float4* xr = (const float4*)(x + (size_t)v * 128);
    float a0 = 0.f, a1 = 0.f, a2 = 0.f, a3 = 0.f;
#pragma unroll
    for (int i = 0; i < 8; ++i) {
        int c = p + i * 4;               // float4 chunk index 0..31 (k = 4c)
        float4 xx = xr[c];
        const float* w = &Ws[c * 16];    // rows k..k+3, 4 outputs each
        a0 += xx.x * w[0] + xx.y * w[4] + xx.z * w[8]  + xx.w * w[12];
        a1 += xx.x * w[1] + xx.y * w[5] + xx.z * w[9]  + xx.w * w[13];
        a2 += xx.x * w[2] + xx.y * w[6] + xx.z * w[10] + xx.w * w[14];
        a3 += xx.x * w[3] + xx.y * w[7] + xx.z * w[11] + xx.w * w[15];
    }
    a0 += __shfl_xor(a0, 1); a0 += __shfl_xor(a0, 2);
    a1 += __shfl_xor(a1, 1); a1 += __shfl_xor(a1, 2);
    a2 += __shfl_xor(a2, 1); a2 += __shfl_xor(a2, 2);
    a3 += __shfl_xor(a3, 1); a3 += __shfl_xor(a3, 2);
    if (p == 0) {
        float di = rsqrtf(dinv[v]);      // dinv[] holds deg; deg >= 1 always
        dinv[v] = di;
        float d2 = di * di;
        ((float4*)h1)[v]   = make_float4(a0, a1, a2, a3);
        ((float4*)agg1)[v] = make_float4(d2 * a0, d2 * a1, d2 * a2, d2 * a3);
    }
}

__global__ void k_edge1(const int* __restrict__ src, const int* __restrict__ dst,
                        const float* __restrict__ dinv, const float* __restrict__ h1,
                        float* __restrict__ agg1, int E) {
    int e = blockIdx.x * blockDim.x + threadIdx.x;
    if (e >= E) return;
    int s = src[e], d = dst[e];
    float nrm = dinv[s] * dinv[d];
    float4 h = ((const float4*)h1)[s];
    float* a = agg1 + 4 * (size_t)d;
    unsafeAtomicAdd(a + 0, nrm * h.x);
    unsafeAtomicAdd(a + 1, nrm * h.y);
    unsafeAtomicAdd(a + 2, nrm * h.z);
    unsafeAtomicAdd(a + 3, nrm * h.w);
}

// out1 = relu(agg1 + b1); h2 = out1 @ W2 (4->2); agg2 init with self-loop.
__global__ void k_node2(const float* __restrict__ agg1, const float* __restrict__ b1,
                        const float* __restrict__ W2, const float* __restrict__ dinv,
                        float* __restrict__ h2, float* __restrict__ agg2, int n) {
    int v = blockIdx.x * blockDim.x + threadIdx.x;
    if (v >= n) return;
    float4 a = ((const float4*)agg1)[v];
    float o0 = fmaxf(a.x + b1[0], 0.f);
    float o1 = fmaxf(a.y + b1[1], 0.f);
    float o2 = fmaxf(a.z + b1[2], 0.f);
    float o3 = fmaxf(a.w + b1[3], 0.f);
    // W2 is [4][2] row-major
    float h0 = o0 * W2[0] + o1 * W2[2] + o2 * W2[4] + o3 * W2[6];
    float h1v = o0 * W2[1] + o1 * W2[3] + o2 * W2[5] + o3 * W2[7];
    float di = dinv[v], d2 = di * di;
    ((float2*)h2)[v]   = make_float2(h0, h1v);
    ((float2*)agg2)[v] = make_float2(d2 * h0, d2 * h1v);
}

__global__ void k_edge2(const int* __restrict__ src, const int* __restrict__ dst,
                        const float* __restrict__ dinv, const float* __restrict__ h2,
                        float* __restrict__ agg2, int E) {
    int e = blockIdx.x * blockDim.x + threadIdx.x;
    if (e >= E) return;
    int s = src[e], d = dst[e];
    float nrm = dinv[s] * dinv[d];
    float2 h = ((const float2*)h2)[s];
    float* a = agg2 + 2 * (size_t)d;
    unsafeAtomicAdd(a + 0, nrm * h.x);
    unsafeAtomicAdd(a + 1, nrm * h.y);
}

// out2 = relu(agg2 + b2); h3 = out2 @ W3 (2->1); agg3 init with self-loop.
__global__ void k_node3(const float* __restrict__ agg2, const float* __restrict__ b2,
                        const float* __restrict__ W3, const float* __restrict__ dinv,
                        float* __restrict__ h3, float* __restrict__ agg3, int n) {
    int v = blockIdx.x * blockDim.x + threadIdx.x;
    if (v >= n) return;
    float2 a = ((const float2*)agg2)[v];
    float o0 = fmaxf(a.x + b2[0], 0.f);
    float o1 = fmaxf(a.y + b2[1], 0.f);
    float hv = o0 * W3[0] + o1 * W3[1];
    float di = dinv[v], d2 = di * di;
    h3[v] = hv;
    agg3[v] = d2 * hv;
}

__global__ void k_edge3(const int* __restrict__ src, const int* __restrict__ dst,
                        const float* __restrict__ dinv, const float* __restrict__ h3,
                        float* __restrict__ agg3, int E) {
    int e = blockIdx.x * blockDim.x + threadIdx.x;
    if (e >= E) return;
    int s = src[e], d = dst[e];
    float nrm = dinv[s] * dinv[d];
    unsafeAtomicAdd(agg3 + d, nrm * h3[s]);
}

__global__ void k_final(const float* __restrict__ agg3, const float* __restrict__ b3,
                        float* __restrict__ out, int n) {
    int v = blockIdx.x * blockDim.x + threadIdx.x;
    if (v >= n) return;
    float t = agg3[v] + b3[0];
    out[v] = 1.0f / (1.0f + __expf(-t));
}

extern "C" void kernel_launch(void* const* d_in, const int* in_sizes, int n_in,
                              void* d_out, int out_size, void* d_ws, size_t ws_size,
                              hipStream_t stream) {
    const float* x  = (const float*)d_in[0];
    const int* ei   = (const int*)d_in[1];
    const float* W1 = (const float*)d_in[2];
    const float* b1 = (const float*)d_in[3];
    const float* W2 = (const float*)d_in[4];
    const float* b2 = (const float*)d_in[5];
    const float* W3 = (const float*)d_in[6];
    const float* b3 = (const float*)d_in[7];
    float* out = (float*)d_out;

    const int N = in_sizes[0] / 128;
    const int E = in_sizes[1] / 2;
    const int* src = ei;
    const int* dst = ei + E;

    float* ws   = (float*)d_ws;
    float* dinv = ws;               // deg -> dinv, N
    float* h1   = ws + (size_t)N;       // 4N
    float* agg1 = ws + (size_t)5 * N;   // 4N
    float* h2   = ws + (size_t)9 * N;   // 2N
    float* agg2 = ws + (size_t)11 * N;  // 2N
    float* h3   = ws + (size_t)13 * N;  // N
    float* agg3 = ws + (size_t)14 * N;  // N

    const int nbN  = (N + TPB - 1) / TPB;
    const int nbN4 = (4 * N + TPB - 1) / TPB;
    const int nbE  = (E + TPB - 1) / TPB;

    k_init_deg<<<nbN, TPB, 0, stream>>>(dinv, N);
    k_count_deg<<<nbE, TPB, 0, stream>>>(dst, dinv, E);
    k_node1<<<nbN4, TPB, 0, stream>>>(x, W1, dinv, h1, agg1, N);
    k_edge1<<<nbE, TPB, 0, stream>>>(src, dst, dinv, h1, agg1, E);
    k_node2<<<nbN, TPB, 0, stream>>>(agg1, b1, W2, dinv, h2, agg2, N);
    k_edge2<<<nbE, TPB, 0, stream>>>(src, dst, dinv, h2, agg2, E);
    k_node3<<<nbN, TPB, 0, stream>>>(agg2, b2, W3, dinv, h3, agg3, N);
    k_edge3<<<nbE, TPB, 0, stream>>>(src, dst, dinv, h3, agg3, E);
    k_final<<<nbN, TPB, 0, stream>>>(agg3, b3, out, N);
}

// Round 2
// 347.233 us; speedup vs baseline: 4.0196x; 4.0196x over previous
//
#include <hip/hip_runtime.h>
#include <hip/hip_bf16.h>
#include <math.h>

// GCN 3-layer inference, CSR-gather restructure.
// N=100000 nodes, E=3200000 edges, feats 128->4->2->1.
// Only atomic pass: histogram-with-return (3.2M int atomics). Aggregation is
// pure gather over per-destination CSR segments built each call.
//
// ws layout: cnt[N] int | off[N] int | lp[E] ushort | ssrc[E] int |
//            dinv[N] f32 | hs1[4N] f32 | hs2[2N] f32 | hs3[N] f32 | gcur[1] int
// ~23 MB total.

#define TPB 256

__global__ void k_zero(int* __restrict__ cnt, int* __restrict__ gcur, int n) {
    int v = blockIdx.x * blockDim.x + threadIdx.x;
    if (v < n) cnt[v] = 0;
    if (v == 0) *gcur = 0;
}

// Pass 1: histogram with return -> per-edge local position.
__global__ void k_pass1(const int* __restrict__ dst, int* __restrict__ cnt,
                        unsigned short* __restrict__ lp, int E) {
    int e = blockIdx.x * blockDim.x + threadIdx.x;
    if (e >= E) return;
    int p = atomicAdd(&cnt[dst[e]], 1);
    lp[e] = (unsigned short)p;
}

// Block-level exclusive scan of cnt -> off (segment bases; inter-block order
// arbitrary via one atomic per block — segments disjoint, which is all the
// gather needs). Also finalize dinv = rsqrt(cnt+1)  (+1 = self-loop).
__global__ __launch_bounds__(TPB) void k_alloc(const int* __restrict__ cnt,
                                               int* __restrict__ off,
                                               float* __restrict__ dinv,
                                               int* __restrict__ gcur, int n) {
    __shared__ int s[TPB];
    __shared__ int base_s;
    int t = threadIdx.x;
    int v = blockIdx.x * TPB + t;
    int c = (v < n) ? cnt[v] : 0;
    s[t] = c;
    __syncthreads();
    int x = c;
    for (int d = 1; d < TPB; d <<= 1) {
        int y = (t >= d) ? s[t - d] : 0;
        __syncthreads();
        x += y;
        s[t] = x;
        __syncthreads();
    }
    if (t == TPB - 1) base_s = atomicAdd(gcur, s[TPB - 1]);
    __syncthreads();
    if (v < n) {
        off[v] = base_s + (x - c);          // exclusive prefix
        dinv[v] = rsqrtf((float)(c + 1));
    }
}

// Pass 2: scatter src indices into CSR order. No atomics.
__global__ void k_pass2(const int* __restrict__ src, const int* __restrict__ dst,
                        const unsigned short* __restrict__ lp,
                        const int* __restrict__ off,
                        int* __restrict__ ssrc, int E) {
    int e = blockIdx.x * blockDim.x + threadIdx.x;
    if (e >= E) return;
    ssrc[off[dst[e]] + (int)lp[e]] = src[e];
}

// Layer-1 GEMM (128->4), write hs1 = dinv * (x@W1).
// Quad-per-node: 4 lanes/node, interleaved float4 chunks, shfl reduce.
__global__ __launch_bounds__(TPB) void k_node1(
    const float* __restrict__ x, const float* __restrict__ W1,
    const float* __restrict__ dinv, float* __restrict__ hs1, int n) {
    __shared__ float Ws[512];  // W1 [128][4] row-major
    for (int i = threadIdx.x; i < 512; i += TPB) Ws[i] = W1[i];
    __syncthreads();
    int t = blockIdx.x * TPB + threadIdx.x;
    int v = t >> 2, p = t & 3;
    if (v >= n) return;
    const float4* xr = (const float4*)(x + (size_t)v * 128);
    float a0 = 0.f, a1 = 0.f, a2 = 0.f, a3 = 0.f;
#pragma unroll
    for (int i = 0; i < 8; ++i) {
        int c = p + i * 4;
        float4 xx = xr[c];
        const float* w = &Ws[c * 16];
        a0 += xx.x * w[0] + xx.y * w[4] + xx.z * w[8]  + xx.w * w[12];
        a1 += xx.x * w[1] + xx.y * w[5] + xx.z * w[9]  + xx.w * w[13];
        a2 += xx.x * w[2] + xx.y * w[6] + xx.z * w[10] + xx.w * w[14];
        a3 += xx.x * w[3] + xx.y * w[7] + xx.z * w[11] + xx.w * w[15];
    }
    a0 += __shfl_xor(a0, 1); a0 += __shfl_xor(a0, 2);
    a1 += __shfl_xor(a1, 1); a1 += __shfl_xor(a1, 2);
    a2 += __shfl_xor(a2, 1); a2 += __shfl_xor(a2, 2);
    a3 += __shfl_xor(a3, 1); a3 += __shfl_xor(a3, 2);
    if (p == 0) {
        float di = dinv[v];
        ((float4*)hs1)[v] = make_float4(di * a0, di * a1, di * a2, di * a3);
    }
}

// Gather layer 1 (float4) + relu + W2 (4->2) -> hs2 = dinv * h2.
__global__ __launch_bounds__(TPB) void k_gather1(
    const int* __restrict__ off, const int* __restrict__ cnt,
    const int* __restrict__ ssrc, const float* __restrict__ hs1,
    const float* __restrict__ dinv, const float* __restrict__ b1,
    const float* __restrict__ W2, float* __restrict__ hs2, int n) {
    int t = blockIdx.x * TPB + threadIdx.x;
    int v = t >> 2, p = t & 3;
    if (v >= n) return;
    int base = off[v], c = cnt[v];
    float4 acc = make_float4(0.f, 0.f, 0.f, 0.f);
    for (int i = p; i < c; i += 4) {
        int s = ssrc[base + i];
        float4 h = ((const float4*)hs1)[s];
        acc.x += h.x; acc.y += h.y; acc.z += h.z; acc.w += h.w;
    }
    acc.x += __shfl_xor(acc.x, 1); acc.x += __shfl_xor(acc.x, 2);
    acc.y += __shfl_xor(acc.y, 1); acc.y += __shfl_xor(acc.y, 2);
    acc.z += __shfl_xor(acc.z, 1); acc.z += __shfl_xor(acc.z, 2);
    acc.w += __shfl_xor(acc.w, 1); acc.w += __shfl_xor(acc.w, 2);
    if (p == 0) {
        float4 hv = ((const float4*)hs1)[v];
        float di = dinv[v];
        float o0 = fmaxf(di * (acc.x + hv.x) + b1[0], 0.f);
        float o1 = fmaxf(di * (acc.y + hv.y) + b1[1], 0.f);
        float o2 = fmaxf(di * (acc.z + hv.z) + b1[2], 0.f);
        float o3 = fmaxf(di * (acc.w + hv.w) + b1[3], 0.f);
        float h0 = o0 * W2[0] + o1 * W2[2] + o2 * W2[4] + o3 * W2[6];
        float h1 = o0 * W2[1] + o1 * W2[3] + o2 * W2[5] + o3 * W2[7];
        ((float2*)hs2)[v] = make_float2(di * h0, di * h1);
    }
}

// Gather layer 2 (float2) + relu + W3 (2->1) -> hs3 = dinv * h3.
__global__ __launch_bounds__(TPB) void k_gather2(
    const int* __restrict__ off, const int* __restrict__ cnt,
    const int* __restrict__ ssrc, const float* __restrict__ hs2,
    const float* __restrict__ dinv, const float* __restrict__ b2,
    const float* __restrict__ W3, float* __restrict__ hs3, int n) {
    int t = blockIdx.x * TPB + threadIdx.x;
    int v = t >> 2, p = t & 3;
    if (v >= n) return;
    int base = off[v], c = cnt[v];
    float2 acc = make_float2(0.f, 0.f);
    for (int i = p; i < c; i += 4) {
        int s = ssrc[base + i];
        float2 h = ((const float2*)hs2)[s];
        acc.x += h.x; acc.y += h.y;
    }
    acc.x += __shfl_xor(acc.x, 1); acc.x += __shfl_xor(acc.x, 2);
    acc.y += __shfl_xor(acc.y, 1); acc.y += __shfl_xor(acc.y, 2);
    if (p == 0) {
        float2 hv = ((const float2*)hs2)[v];
        float di = dinv[v];
        float o0 = fmaxf(di * (acc.x + hv.x) + b2[0], 0.f);
        float o1 = fmaxf(di * (acc.y + hv.y) + b2[1], 0.f);
        float h3 = o0 * W3[0] + o1 * W3[1];
        hs3[v] = di * h3;
    }
}

// Gather layer 3 (float) + bias + sigmoid -> out.
__global__ __launch_bounds__(TPB) void k_gather3(
    const int* __restrict__ off, const int* __restrict__ cnt,
    const int* __restrict__ ssrc, const float* __restrict__ hs3,
    const float* __restrict__ dinv, const float* __restrict__ b3,
    float* __restrict__ out, int n) {
    int t = blockIdx.x * TPB + threadIdx.x;
    int v = t >> 2, p = t & 3;
    if (v >= n) return;
    int base = off[v], c = cnt[v];
    float acc = 0.f;
    for (int i = p; i < c; i += 4) acc += hs3[ssrc[base + i]];
    acc += __shfl_xor(acc, 1); acc += __shfl_xor(acc, 2);
    if (p == 0) {
        float di = dinv[v];
        float agg = di * (acc + hs3[v]) + b3[0];
        out[v] = 1.0f / (1.0f + __expf(-agg));
    }
}

extern "C" void kernel_launch(void* const* d_in, const int* in_sizes, int n_in,
                              void* d_out, int out_size, void* d_ws, size_t ws_size,
                              hipStream_t stream) {
    const float* x  = (const float*)d_in[0];
    const int* ei   = (const int*)d_in[1];
    const float* W1 = (const float*)d_in[2];
    const float* b1 = (const float*)d_in[3];
    const float* W2 = (const float*)d_in[4];
    const float* b2 = (const float*)d_in[5];
    const float* W3 = (const float*)d_in[6];
    const float* b3 = (const float*)d_in[7];
    float* out = (float*)d_out;

    const int N = in_sizes[0] / 128;
    const int E = in_sizes[1] / 2;
    const int* src = ei;
    const int* dst = ei + E;

    char* w = (char*)d_ws;
    int* cnt            = (int*)w;                 w += (size_t)N * 4;
    int* off            = (int*)w;                 w += (size_t)N * 4;
    unsigned short* lp  = (unsigned short*)w;      w += (size_t)E * 2;
    int* ssrc           = (int*)w;                 w += (size_t)E * 4;
    float* dinv         = (float*)w;               w += (size_t)N * 4;
    float* hs1          = (float*)w;               w += (size_t)N * 16;
    float* hs2          = (float*)w;               w += (size_t)N * 8;
    float* hs3          = (float*)w;               w += (size_t)N * 4;
    int* gcur           = (int*)w;

    const int nbN  = (N + TPB - 1) / TPB;
    const int nbN4 = (4 * N + TPB - 1) / TPB;
    const int nbE  = (E + TPB - 1) / TPB;

    k_zero<<<nbN, TPB, 0, stream>>>(cnt, gcur, N);
    k_pass1<<<nbE, TPB, 0, stream>>>(dst, cnt, lp, E);
    k_alloc<<<nbN, TPB, 0, stream>>>(cnt, off, dinv, gcur, N);
    k_pass2<<<nbE, TPB, 0, stream>>>(src, dst, lp, off, ssrc, E);
    k_node1<<<nbN4, TPB, 0, stream>>>(x, W1, dinv, hs1, N);
    k_gather1<<<nbN4, TPB, 0, stream>>>(off, cnt, ssrc, hs1, dinv, b1, W2, hs2, N);
    k_gather2<<<nbN4, TPB, 0, stream>>>(off, cnt, ssrc, hs2, dinv, b2, W3, hs3, N);
    k_gather3<<<nbN4, TPB, 0, stream>>>(off, cnt, ssrc, hs3, dinv, b3, out, N);
}

// Round 3
// 246.798 us; speedup vs baseline: 5.6554x; 1.4070x over previous
//
#include <hip/hip_runtime.h>
#include <hip/hip_bf16.h>
#include <math.h>

// GCN 3-layer inference. N=100000, E=3200000, feats 128->4->2->1.
// R3: CSR build via two-level counting sort — ZERO device-scope atomics
// (R2's k_pass1 showed device atomics cap at ~24 G/s = 132 us; LDS atomics
// are CU-local and effectively free at this scale).
//
// Level 1: partition edges into NB=ceil(N/256) coarse buckets by dst>>8
//          (block-local LDS histograms -> scan -> scatter, classic radix pass).
// Level 2: one block per bucket: LDS count per node -> LDS scan -> counting
//          sort into final CSR ssrc. off[v] = binBase[bucket] + local_off.
// Gathers (unchanged math from R2, absmax was 0.0).

#define TPB 256
#define CHUNK 4096      // edges per block in level-1 passes
#define NB_MAX 512      // max coarse buckets (N <= 131072)

__global__ __launch_bounds__(TPB) void k_hist(const int* __restrict__ dst,
                                              int* __restrict__ histT,
                                              int nblk, int NB, int E) {
    __shared__ int h[NB_MAX];
    for (int i = threadIdx.x; i < NB; i += TPB) h[i] = 0;
    __syncthreads();
    int base = blockIdx.x * CHUNK;
    int end = min(base + CHUNK, E);
    for (int e = base + threadIdx.x; e < end; e += TPB)
        atomicAdd(&h[dst[e] >> 8], 1);
    __syncthreads();
    for (int i = threadIdx.x; i < NB; i += TPB)
        histT[(size_t)i * nblk + blockIdx.x] = h[i];
}

// One block per bin: exclusive-scan histT[bin][0..nblk) in place; binTotal out.
__global__ __launch_bounds__(TPB) void k_scanA(int* __restrict__ histT,
                                               int* __restrict__ binTotal, int nblk) {
    __shared__ int s[TPB];
    int* row = histT + (size_t)blockIdx.x * nblk;
    int t = threadIdx.x;
    int run = 0;
    for (int base = 0; base < nblk; base += TPB) {
        int i = base + t;
        int v = (i < nblk) ? row[i] : 0;
        s[t] = v;
        __syncthreads();
        int x = v;
        for (int d = 1; d < TPB; d <<= 1) {
            int y = (t >= d) ? s[t - d] : 0;
            __syncthreads();
            x += y;
            s[t] = x;
            __syncthreads();
        }
        if (i < nblk) row[i] = run + (x - v);   // exclusive prefix
        run += s[TPB - 1];
        __syncthreads();
    }
    if (t == 0) binTotal[blockIdx.x] = run;
}

// Single block of 512: exclusive scan binTotal[NB] -> binBase[NB].
__global__ __launch_bounds__(512) void k_scanB(const int* __restrict__ binTotal,
                                               int* __restrict__ binBase, int NB) {
    __shared__ int s[512];
    int t = threadIdx.x;
    int v = (t < NB) ? binTotal[t] : 0;
    s[t] = v;
    __syncthreads();
    int x = v;
    for (int d = 1; d < 512; d <<= 1) {
        int y = (t >= d) ? s[t - d] : 0;
        __syncthreads();
        x += y;
        s[t] = x;
        __syncthreads();
    }
    if (t < NB) binBase[t] = x - v;
}

// Scatter edges into coarse-bucket runs. pairs = src | (dst&255)<<17.
__global__ __launch_bounds__(TPB) void k_scatter1(
    const int* __restrict__ src, const int* __restrict__ dst,
    const int* __restrict__ histT, const int* __restrict__ binBase,
    unsigned int* __restrict__ pairs, int nblk, int NB, int E) {
    __shared__ int cur[NB_MAX];
    int blk = blockIdx.x;
    for (int i = threadIdx.x; i < NB; i += TPB)
        cur[i] = binBase[i] + histT[(size_t)i * nblk + blk];
    __syncthreads();
    int base = blk * CHUNK;
    int end = min(base + CHUNK, E);
    for (int e = base + threadIdx.x; e < end; e += TPB) {
        int d = dst[e];
        int pos = atomicAdd(&cur[d >> 8], 1);
        pairs[pos] = (unsigned)src[e] | ((unsigned)(d & 255) << 17);
    }
}

// One block per bucket: counting sort into final CSR; cnt/off/dinv out.
__global__ __launch_bounds__(TPB) void k_bucket(
    const unsigned int* __restrict__ pairs, const int* __restrict__ binBase,
    const int* __restrict__ binTotal, int* __restrict__ cnt,
    int* __restrict__ off, float* __restrict__ dinv,
    int* __restrict__ ssrc, int N) {
    __shared__ int c[TPB], s[TPB];
    int b = blockIdx.x, t = threadIdx.x;
    c[t] = 0;
    __syncthreads();
    int pb = binBase[b], nb = binTotal[b];
    for (int i = t; i < nb; i += TPB)
        atomicAdd(&c[pairs[pb + i] >> 17], 1);
    __syncthreads();
    int cv = c[t];
    s[t] = cv;
    __syncthreads();
    int x = cv;
    for (int d = 1; d < TPB; d <<= 1) {
        int y = (t >= d) ? s[t - d] : 0;
        __syncthreads();
        x += y;
        s[t] = x;
        __syncthreads();
    }
    int excl = x - cv;
    int v = (b << 8) + t;
    if (v < N) {
        cnt[v] = cv;
        off[v] = pb + excl;
        dinv[v] = rsqrtf((float)(cv + 1));
    }
    s[t] = excl;                // cursors
    __syncthreads();
    for (int i = t; i < nb; i += TPB) {
        unsigned p = pairs[pb + i];
        int pos = atomicAdd(&s[p >> 17], 1);
        ssrc[pb + pos] = (int)(p & 0x1FFFFu);
    }
}

// Layer-1 GEMM (128->4): hs1 = dinv * (x@W1). Quad-per-node, shfl reduce.
__global__ __launch_bounds__(TPB) void k_node1(
    const float* __restrict__ x, const float* __restrict__ W1,
    const float* __restrict__ dinv, float* __restrict__ hs1, int n) {
    __shared__ float Ws[512];  // W1 [128][4] row-major
    for (int i = threadIdx.x; i < 512; i += TPB) Ws[i] = W1[i];
    __syncthreads();
    int t = blockIdx.x * TPB + threadIdx.x;
    int v = t >> 2, p = t & 3;
    if (v >= n) return;
    const float4* xr = (const float4*)(x + (size_t)v * 128);
    float a0 = 0.f, a1 = 0.f, a2 = 0.f, a3 = 0.f;
#pragma unroll
    for (int i = 0; i < 8; ++i) {
        int c = p + i * 4;
        float4 xx = xr[c];
        const float* w = &Ws[c * 16];
        a0 += xx.x * w[0] + xx.y * w[4] + xx.z * w[8]  + xx.w * w[12];
        a1 += xx.x * w[1] + xx.y * w[5] + xx.z * w[9]  + xx.w * w[13];
        a2 += xx.x * w[2] + xx.y * w[6] + xx.z * w[10] + xx.w * w[14];
        a3 += xx.x * w[3] + xx.y * w[7] + xx.z * w[11] + xx.w * w[15];
    }
    a0 += __shfl_xor(a0, 1); a0 += __shfl_xor(a0, 2);
    a1 += __shfl_xor(a1, 1); a1 += __shfl_xor(a1, 2);
    a2 += __shfl_xor(a2, 1); a2 += __shfl_xor(a2, 2);
    a3 += __shfl_xor(a3, 1); a3 += __shfl_xor(a3, 2);
    if (p == 0) {
        float di = dinv[v];
        ((float4*)hs1)[v] = make_float4(di * a0, di * a1, di * a2, di * a3);
    }
}

__global__ __launch_bounds__(TPB) void k_gather1(
    const int* __restrict__ off, const int* __restrict__ cnt,
    const int* __restrict__ ssrc, const float* __restrict__ hs1,
    const float* __restrict__ dinv, const float* __restrict__ b1,
    const float* __restrict__ W2, float* __restrict__ hs2, int n) {
    int t = blockIdx.x * TPB + threadIdx.x;
    int v = t >> 2, p = t & 3;
    if (v >= n) return;
    int base = off[v], c = cnt[v];
    float4 acc = make_float4(0.f, 0.f, 0.f, 0.f);
    for (int i = p; i < c; i += 4) {
        int s = ssrc[base + i];
        float4 h = ((const float4*)hs1)[s];
        acc.x += h.x; acc.y += h.y; acc.z += h.z; acc.w += h.w;
    }
    acc.x += __shfl_xor(acc.x, 1); acc.x += __shfl_xor(acc.x, 2);
    acc.y += __shfl_xor(acc.y, 1); acc.y += __shfl_xor(acc.y, 2);
    acc.z += __shfl_xor(acc.z, 1); acc.z += __shfl_xor(acc.z, 2);
    acc.w += __shfl_xor(acc.w, 1); acc.w += __shfl_xor(acc.w, 2);
    if (p == 0) {
        float4 hv = ((const float4*)hs1)[v];
        float di = dinv[v];
        float o0 = fmaxf(di * (acc.x + hv.x) + b1[0], 0.f);
        float o1 = fmaxf(di * (acc.y + hv.y) + b1[1], 0.f);
        float o2 = fmaxf(di * (acc.z + hv.z) + b1[2], 0.f);
        float o3 = fmaxf(di * (acc.w + hv.w) + b1[3], 0.f);
        float h0 = o0 * W2[0] + o1 * W2[2] + o2 * W2[4] + o3 * W2[6];
        float h1 = o0 * W2[1] + o1 * W2[3] + o2 * W2[5] + o3 * W2[7];
        ((float2*)hs2)[v] = make_float2(di * h0, di * h1);
    }
}

__global__ __launch_bounds__(TPB) void k_gather2(
    const int* __restrict__ off, const int* __restrict__ cnt,
    const int* __restrict__ ssrc, const float* __restrict__ hs2,
    const float* __restrict__ dinv, const float* __restrict__ b2,
    const float* __restrict__ W3, float* __restrict__ hs3, int n) {
    int t = blockIdx.x * TPB + threadIdx.x;
    int v = t >> 2, p = t & 3;
    if (v >= n) return;
    int base = off[v], c = cnt[v];
    float2 acc = make_float2(0.f, 0.f);
    for (int i = p; i < c; i += 4) {
        int s = ssrc[base + i];
        float2 h = ((const float2*)hs2)[s];
        acc.x += h.x; acc.y += h.y;
    }
    acc.x += __shfl_xor(acc.x, 1); acc.x += __shfl_xor(acc.x, 2);
    acc.y += __shfl_xor(acc.y, 1); acc.y += __shfl_xor(acc.y, 2);
    if (p == 0) {
        float2 hv = ((const float2*)hs2)[v];
        float di = dinv[v];
        float o0 = fmaxf(di * (acc.x + hv.x) + b2[0], 0.f);
        float o1 = fmaxf(di * (acc.y + hv.y) + b2[1], 0.f);
        float h3 = o0 * W3[0] + o1 * W3[1];
        hs3[v] = di * h3;
    }
}

__global__ __launch_bounds__(TPB) void k_gather3(
    const int* __restrict__ off, const int* __restrict__ cnt,
    const int* __restrict__ ssrc, const float* __restrict__ hs3,
    const float* __restrict__ dinv, const float* __restrict__ b3,
    float* __restrict__ out, int n) {
    int t = blockIdx.x * TPB + threadIdx.x;
    int v = t >> 2, p = t & 3;
    if (v >= n) return;
    int base = off[v], c = cnt[v];
    float acc = 0.f;
    for (int i = p; i < c; i += 4) acc += hs3[ssrc[base + i]];
    acc += __shfl_xor(acc, 1); acc += __shfl_xor(acc, 2);
    if (p == 0) {
        float di = dinv[v];
        float agg = di * (acc + hs3[v]) + b3[0];
        out[v] = 1.0f / (1.0f + __expf(-agg));
    }
}

extern "C" void kernel_launch(void* const* d_in, const int* in_sizes, int n_in,
                              void* d_out, int out_size, void* d_ws, size_t ws_size,
                              hipStream_t stream) {
    const float* x  = (const float*)d_in[0];
    const int* ei   = (const int*)d_in[1];
    const float* W1 = (const float*)d_in[2];
    const float* b1 = (const float*)d_in[3];
    const float* W2 = (const float*)d_in[4];
    const float* b2 = (const float*)d_in[5];
    const float* W3 = (const float*)d_in[6];
    const float* b3 = (const float*)d_in[7];
    float* out = (float*)d_out;

    const int N = in_sizes[0] / 128;
    const int E = in_sizes[1] / 2;
    const int* src = ei;
    const int* dst = ei + E;

    const int nblk = (E + CHUNK - 1) / CHUNK;   // level-1 edge blocks
    const int NB   = (N + 255) >> 8;            // coarse buckets (<= NB_MAX)

    // ws carve (16B-aligned chunks). pairs region is reused for hs* after
    // k_bucket (stream-ordered: node1/gathers run after bucket).
    char* w = (char*)d_ws;
    auto carve = [&](size_t bytes) { char* p = w; w += (bytes + 15) & ~(size_t)15; return p; };
    int* histT    = (int*)carve((size_t)nblk * NB * 4);
    int* binTotal = (int*)carve((size_t)NB * 4);
    int* binBase  = (int*)carve((size_t)NB * 4);
    int* cnt      = (int*)carve((size_t)N * 4);
    int* off      = (int*)carve((size_t)N * 4);
    float* dinv   = (float*)carve((size_t)N * 4);
    int* ssrc     = (int*)carve((size_t)E * 4);
    unsigned int* pairs = (unsigned int*)carve((size_t)E * 4);
    float* hs1 = (float*)pairs;                  // 4N floats  (overlay)
    float* hs2 = hs1 + (size_t)4 * N;            // 2N floats
    float* hs3 = hs2 + (size_t)2 * N;            // N floats

    const int nbN4 = (4 * N + TPB - 1) / TPB;

    k_hist    <<<nblk, TPB, 0, stream>>>(dst, histT, nblk, NB, E);
    k_scanA   <<<NB,   TPB, 0, stream>>>(histT, binTotal, nblk);
    k_scanB   <<<1,    512, 0, stream>>>(binTotal, binBase, NB);
    k_scatter1<<<nblk, TPB, 0, stream>>>(src, dst, histT, binBase, pairs, nblk, NB, E);
    k_bucket  <<<NB,   TPB, 0, stream>>>(pairs, binBase, binTotal, cnt, off, dinv, ssrc, N);
    k_node1   <<<nbN4, TPB, 0, stream>>>(x, W1, dinv, hs1, N);
    k_gather1 <<<nbN4, TPB, 0, stream>>>(off, cnt, ssrc, hs1, dinv, b1, W2, hs2, N);
    k_gather2 <<<nbN4, TPB, 0, stream>>>(off, cnt, ssrc, hs2, dinv, b2, W3, hs3, N);
    k_gather3 <<<nbN4, TPB, 0, stream>>>(off, cnt, ssrc, hs3, dinv, b3, out, N);
}